// Round 9
// baseline (192.373 us; speedup 1.0000x reference)
//
#include <hip/hip_runtime.h>
#include <hip/hip_bf16.h>

typedef __bf16 bf16;
typedef __bf16 bf16x4 __attribute__((ext_vector_type(4)));
typedef __bf16 bf16x8 __attribute__((ext_vector_type(8)));
typedef float  f32x16 __attribute__((ext_vector_type(16)));

#define MFMA32 __builtin_amdgcn_mfma_f32_32x32x16_bf16
#define EPSV 1e-5f
#define QSCALE 0.36067376022224085f  /* 0.25 * log2(e) */

__device__ __forceinline__ f32x16 fzero16() {
  f32x16 z;
#pragma unroll
  for (int i = 0; i < 16; ++i) z[i] = 0.f;
  return z;
}

/* ---------------- kernel 1a: per-batch partial sums over x1 ---------------- */
__global__ __launch_bounds__(256) void k_stats_partial(const float* __restrict__ x,
                                                       float* __restrict__ part) {
  const int b = blockIdx.x >> 5, k = blockIdx.x & 31;
  const float* p = x + (size_t)b * 256 * 4096 + k * 8192;
  const int t = threadIdx.x;
  float s = 0.f, q = 0.f;
#pragma unroll
  for (int j = 0; j < 8; ++j) {
    float4 v = ((const float4*)p)[t + j * 256];
    s += v.x + v.y + v.z + v.w;
    q += v.x * v.x + v.y * v.y + v.z * v.z + v.w * v.w;
  }
  __shared__ float ls[256], lq[256];
  ls[t] = s; lq[t] = q;
  __syncthreads();
  for (int off = 128; off > 0; off >>= 1) {
    if (t < off) { ls[t] += ls[t + off]; lq[t] += lq[t + off]; }
    __syncthreads();
  }
  if (t == 0) { part[blockIdx.x * 2] = ls[0]; part[blockIdx.x * 2 + 1] = lq[0]; }
}

/* ---------------- kernel 1b: finalize mu / rstd per batch ---------------- */
__global__ __launch_bounds__(256) void k_stats_final(const float* __restrict__ part,
                                                     float* __restrict__ stats) {
  const int t = threadIdx.x, b = t >> 5, k = t & 31;
  float s = part[(b * 32 + k) * 2], q = part[(b * 32 + k) * 2 + 1];
  for (int off = 16; off > 0; off >>= 1) {
    s += __shfl_down(s, off, 32);
    q += __shfl_down(q, off, 32);
  }
  if (k == 0) {
    const float inv_n = 1.f / 262144.f;
    const float mu = s * inv_n;
    const float var = q * inv_n - mu * mu;
    stats[b * 2] = mu;
    stats[b * 2 + 1] = rsqrtf(var + EPSV);
  }
}

/* ------- kernel 2: GN-normalize x1, qkv matmul + BN, emit q/k/v bf16 -------
   V written in MFMA-FRAGMENT-MAJOR layout: vf[IT][f][lane][16B], where
   slot j of lane l = V[c=(l&31)+32*(f&1)][m=(j&3)+4*(l>>5)+8*(j>>2)+16*(f>>1)]
   (IT = global 32-key tile). Attention then loads V fully coalesced.        */
__global__ __launch_bounds__(256) void k_qkv(
    const float* __restrict__ x, const float* __restrict__ gn_g, const float* __restrict__ gn_b,
    const float* __restrict__ qkv_w, const float* __restrict__ bn_g, const float* __restrict__ bn_b,
    const float* __restrict__ bn_rm, const float* __restrict__ bn_rv,
    const float* __restrict__ stats,
    bf16* __restrict__ qw, bf16* __restrict__ kw, bf16* __restrict__ vw) {
  const int b = blockIdx.x >> 6, tile = blockIdx.x & 63;
  const int n0 = tile * 64, t = threadIdx.x;
  __shared__ float xn[64][68];
  __shared__ float W[64][96];
  __shared__ float beta_s[96];
  const float mu = stats[b * 2], rstd = stats[b * 2 + 1];
  {
    const int c = t >> 2, f = t & 3;
    const float A = rstd * gn_g[c], B = gn_b[c] - mu * A;
    const float* xr = x + ((size_t)b * 256 + c) * 4096 + n0;
#pragma unroll
    for (int j = 0; j < 4; ++j) {
      float4 v = ((const float4*)xr)[f * 4 + j];
      const int nb = f * 16 + j * 4;
      xn[c][nb + 0] = v.x * A + B; xn[c][nb + 1] = v.y * A + B;
      xn[c][nb + 2] = v.z * A + B; xn[c][nb + 3] = v.w * A + B;
    }
  }
  for (int oc = t; oc < 96 * 8; oc += 256) {
    const int o = oc >> 3, ch = (oc & 7) * 8;
    const float inv = bn_g[o] * rsqrtf(bn_rv[o] + EPSV);
    if (ch == 0) beta_s[o] = bn_b[o] - bn_rm[o] * inv;
    const float* wr = qkv_w + o * 64 + ch;
#pragma unroll
    for (int i = 0; i < 8; ++i) W[ch + i][o] = wr[i] * inv;
  }
  __syncthreads();
  const int o_l = t & 31, ng = t >> 5;
#pragma unroll 1
  for (int p = 0; p < 3; ++p) {
    const int o = p * 32 + o_l;
    float acc[8];
#pragma unroll
    for (int j = 0; j < 8; ++j) acc[j] = 0.f;
    for (int c = 0; c < 64; ++c) {
      const float wv = W[c][o];
      const float* xr = &xn[c][ng * 8];
#pragma unroll
      for (int j = 0; j < 8; ++j) acc[j] += wv * xr[j];
    }
    const float beta = beta_s[o];
    const int nb = n0 + ng * 8;
    if (p == 0) {
      if (o < 16) {
#pragma unroll
        for (int j = 0; j < 8; ++j)
          qw[((size_t)b * 4096 + nb + j) * 16 + o] = (bf16)((acc[j] + beta) * QSCALE);
      } else {
#pragma unroll
        for (int j = 0; j < 8; ++j)
          kw[((size_t)b * 4096 + nb + j) * 16 + (o - 16)] = (bf16)(acc[j] + beta);
      }
    } else {
      const int c = (p - 1) * 32 + o_l;
      /* fragment-major V store: thread owns (c, keys nb..nb+7) */
      const int IT = nb >> 5;             /* global 32-key tile   */
      const int m4 = nb & 31;             /* 0,8,16,24            */
      const int f  = ((m4 >> 4) << 1) + (c >> 5);
      const int b3 = (m4 >> 3) & 1;
      char* base = (char*)vw + (size_t)b * 524288 + (size_t)IT * 4096 +
                   f * 1024 + (c & 31) * 16 + b3 * 8;
      bf16x4 pk0, pk1;
#pragma unroll
      for (int i = 0; i < 4; ++i) {
        pk0[i] = (bf16)(acc[i] + beta);       /* keys m4..m4+3  -> lane c&31      */
        pk1[i] = (bf16)(acc[4 + i] + beta);   /* keys m4+4..+7  -> lane (c&31)+32 */
      }
      *(bf16x4*)base = pk0;
      *(bf16x4*)(base + 512) = pk1;
    }
  }
}

/* --------------- kernel 3: LDS-free flash attention, hi-occupancy -----------
   grid 1024 (XCD-swizzled, batch-per-XCD); 512 thr = 8 waves = 8 key-ranges
   of 512 keys, all for the SAME 32 queries. 4 blocks/CU -> 8 waves/SIMD.
   Main loop: coalesced K (1KB, prefetched 1-deep) + fragment-major V
   (4x coalesced 1KB); zero LDS ops / barriers. End: in-LDS 8-way split-K
   combine + fused relu(x2) transpose.                                        */
__global__ __launch_bounds__(512, 8) void k_attn(
    const bf16* __restrict__ qw, const bf16* __restrict__ kw,
    const bf16* __restrict__ vw, const float* __restrict__ x,
    bf16* __restrict__ xc) {
  __shared__ __align__(16) char smem[33792];   /* 8x4KB Opart + 8x128B l */
  const int orig = blockIdx.x;
  const int wg = (orig & 7) * 128 + (orig >> 3);  /* XCD j <- batch j */
  const int b = wg >> 7, qblk = wg & 127;
  const int t = threadIdx.x;
  const int wid = t >> 6, l = t & 63, ln = l & 31, g = l >> 5;
  const int m0 = wid * 512;

  const bf16* qb = qw + (size_t)b * 4096 * 16;
  const char* kb = (const char*)(kw + (size_t)b * 4096 * 16);
  const char* vfb = (const char*)vw + (size_t)b * 524288;

  const char* kptr = kb + (size_t)(m0 + ln) * 32 + 16 * g;
  const char* vptr = vfb + (size_t)(m0 >> 5) * 4096 + l * 16;

  const int nq = qblk * 32 + ln;
  const bf16x8 qf = *(const bf16x8*)(qb + (size_t)nq * 16 + g * 8);

  f32x16 O0 = fzero16(), O1 = fzero16();
  float l_run = 0.f;

  uint4 kc = *(const uint4*)kptr;   /* prefetch iter 0's K */
#pragma unroll 1
  for (int it = 0; it < 16; ++it) {
    const uint4 va0 = *(const uint4*)(vptr + it * 4096);          /* c=ln,    m 0-15  */
    const uint4 vb0 = *(const uint4*)(vptr + it * 4096 + 1024);   /* c=ln+32, m 0-15  */
    const uint4 va1 = *(const uint4*)(vptr + it * 4096 + 2048);   /* c=ln,    m 16-31 */
    const uint4 vb1 = *(const uint4*)(vptr + it * 4096 + 3072);   /* c=ln+32, m 16-31 */
    const uint4 kcur = kc;
    if (it + 1 < 16) kc = *(const uint4*)(kptr + (it + 1) * 1024);  /* prefetch */
    /* QK^T: S[key m][query n], n = ln lane-local */
    f32x16 S = MFMA32(__builtin_bit_cast(bf16x8, kcur), qf, fzero16(), 0, 0, 0);
    float ts = 0.f;
#pragma unroll
    for (int r = 0; r < 16; ++r) { S[r] = __builtin_amdgcn_exp2f(S[r]); ts += S[r]; }
    ts += __shfl_xor(ts, 32, 64);
    l_run += ts;
    bf16x8 pb0, pb1;
#pragma unroll
    for (int r = 0; r < 8; ++r) { pb0[r] = (bf16)S[r]; pb1[r] = (bf16)S[r + 8]; }
    /* PV: 4 MFMAs, fragments straight from coalesced loads */
    O0 = MFMA32(__builtin_bit_cast(bf16x8, va0), pb0, O0, 0, 0, 0);
    O1 = MFMA32(__builtin_bit_cast(bf16x8, vb0), pb0, O1, 0, 0, 0);
    O0 = MFMA32(__builtin_bit_cast(bf16x8, va1), pb1, O0, 0, 0, 0);
    O1 = MFMA32(__builtin_bit_cast(bf16x8, vb1), pb1, O1, 0, 0, 0);
  }

  /* partials into own LDS slice: Opart[wid][n 32][16 x 8B chunks] swizzled */
  {
    char* orow = smem + wid * 4096 + ln * 128;
    const int msk = 2 * (ln & 7);
#pragma unroll
    for (int h = 0; h < 2; ++h) {
      const f32x16& O = h ? O1 : O0;
#pragma unroll
      for (int j = 0; j < 4; ++j) {
        bf16x4 e;
#pragma unroll
        for (int i = 0; i < 4; ++i) e[i] = (bf16)O[4 * j + i];
        const int chunk = h * 8 + 2 * j + g;
        *(bf16x4*)(orow + ((chunk ^ msk) << 3)) = e;
      }
    }
    if (g == 0) *(float*)(smem + 32768 + wid * 128 + ln * 4) = l_run;
  }
  __syncthreads();

  /* combine 8 key-range partials -> xc[:,0:64]; thread owns (n, chunk of 4c) */
  {
    const int n = t >> 4, chunk = t & 15;
    const int off = ((chunk ^ (2 * (n & 7))) << 3);
    float L = 0.f;
    float acc[4];
#pragma unroll
    for (int e = 0; e < 4; ++e) acc[e] = 0.f;
#pragma unroll
    for (int w_ = 0; w_ < 8; ++w_) {
      L += *(const float*)(smem + 32768 + w_ * 128 + n * 4);
      const bf16x4 v = *(const bf16x4*)(smem + w_ * 4096 + n * 128 + off);
#pragma unroll
      for (int e = 0; e < 4; ++e) acc[e] += (float)v[e];
    }
    const float rL = 1.0f / L;
    bf16x4 o4;
#pragma unroll
    for (int e = 0; e < 4; ++e) o4[e] = (bf16)fmaxf(acc[e] * rL, 0.f);
    *(bf16x4*)(xc + ((size_t)b * 4096 + qblk * 32 + n) * 256 + chunk * 4) = o4;
  }
  __syncthreads();

  /* fused prep_x2: relu(x2) -> bf16 transpose into xc[n][64:256] (32 rows) */
  {
    unsigned* tile_u = (unsigned*)smem;  /* [32 n][97 stride] words */
    const float* xb = x + ((size_t)b * 256 + 64) * 4096 + qblk * 32;
#pragma unroll
    for (int i = 0; i < 2; ++i) {
      const int idx = i * 512 + t;
      if (idx < 768) {
        const int cp = idx >> 3, f = idx & 7;
        const float4 a = *(const float4*)(xb + (size_t)(2 * cp) * 4096 + f * 4);
        const float4 c4 = *(const float4*)(xb + (size_t)(2 * cp + 1) * 4096 + f * 4);
        const float av[4] = {a.x, a.y, a.z, a.w};
        const float cv[4] = {c4.x, c4.y, c4.z, c4.w};
#pragma unroll
        for (int e = 0; e < 4; ++e) {
          const unsigned u =
              (unsigned)__builtin_bit_cast(unsigned short, (bf16)fmaxf(av[e], 0.f)) |
              ((unsigned)__builtin_bit_cast(unsigned short, (bf16)fmaxf(cv[e], 0.f)) << 16);
          tile_u[(f * 4 + e) * 97 + cp] = u;
        }
      }
    }
    __syncthreads();
#pragma unroll
    for (int i = 0; i < 2; ++i) {
      const int idx = i * 512 + t;
      if (idx < 768) {
        const int n = idx / 24, q = idx % 24;
        const uint4 d = *(const uint4*)&tile_u[n * 97 + q * 4];
        *(uint4*)(xc + ((size_t)b * 4096 + qblk * 32 + n) * 256 + 64 + q * 8) = d;
      }
    }
  }
}

/* ---------- kernel 4: proj matmul (MFMA bf16) + BN, 128n x 128o tile ---------- */
__global__ __launch_bounds__(256, 2) void k_proj(
    const bf16* __restrict__ xc, const float* __restrict__ pw,
    const float* __restrict__ bn_g, const float* __restrict__ bn_b,
    const float* __restrict__ bn_rm, const float* __restrict__ bn_rv,
    float* __restrict__ out) {
  const int orig = blockIdx.x;
  const int wg = (orig & 7) * 64 + (orig >> 3);  /* XCD swizzle, 512 blocks */
  const int b = wg >> 6, rem = wg & 63, nt = rem >> 1, oh = rem & 1;
  const int n0 = nt * 128, o0 = oh * 128;
  const int t = threadIdx.x, w = t >> 6, l = t & 63, ln = l & 31, g = l >> 5;

  __shared__ __align__(16) bf16 pws[128 * 256];
  __shared__ float beta_s[128];

  {
    const int o = t >> 1, half = t & 1;
    const float inv = bn_g[o0 + o] * rsqrtf(bn_rv[o0 + o] + EPSV);
    if (half == 0) beta_s[o] = bn_b[o0 + o] - bn_rm[o0 + o] * inv;
    const float* wr = pw + (size_t)(o0 + o) * 256 + half * 128;
    const int s_hh = (o & 15) * 8;
#pragma unroll
    for (int j = 0; j < 16; ++j) {
      const float4 a = ((const float4*)wr)[j * 2];
      const float4 c4 = ((const float4*)wr)[j * 2 + 1];
      bf16x8 v8;
      v8[0] = (bf16)(a.x * inv);  v8[1] = (bf16)(a.y * inv);
      v8[2] = (bf16)(a.z * inv);  v8[3] = (bf16)(a.w * inv);
      v8[4] = (bf16)(c4.x * inv); v8[5] = (bf16)(c4.y * inv);
      v8[6] = (bf16)(c4.z * inv); v8[7] = (bf16)(c4.w * inv);
      *(bf16x8*)&pws[o * 256 + ((half * 128 + j * 8) ^ s_hh)] = v8;
    }
  }
  __syncthreads();

  const bf16* xrow = xc + ((size_t)b * 4096 + n0 + w * 32 + ln) * 256;
  const int sw = (ln & 15) * 8;
  f32x16 acc0 = fzero16(), acc1 = fzero16(), acc2 = fzero16(), acc3 = fzero16();
#pragma unroll 4
  for (int ck = 0; ck < 256; ck += 16) {
    const bf16x8 bfrag = *(const bf16x8*)(xrow + ck + g * 8);
    const int cidx = (ck + g * 8) ^ sw;
    const bf16x8 a0 = *(const bf16x8*)&pws[(ln) * 256 + cidx];
    const bf16x8 a1 = *(const bf16x8*)&pws[(32 + ln) * 256 + cidx];
    const bf16x8 a2 = *(const bf16x8*)&pws[(64 + ln) * 256 + cidx];
    const bf16x8 a3 = *(const bf16x8*)&pws[(96 + ln) * 256 + cidx];
    acc0 = MFMA32(a0, bfrag, acc0, 0, 0, 0);
    acc1 = MFMA32(a1, bfrag, acc1, 0, 0, 0);
    acc2 = MFMA32(a2, bfrag, acc2, 0, 0, 0);
    acc3 = MFMA32(a3, bfrag, acc3, 0, 0, 0);
  }
  const int ncol = n0 + w * 32 + ln;
  float* ob = out + (size_t)b * 256 * 4096 + ncol;
#pragma unroll
  for (int og = 0; og < 4; ++og) {
    const f32x16& A = og == 0 ? acc0 : og == 1 ? acc1 : og == 2 ? acc2 : acc3;
#pragma unroll
    for (int r = 0; r < 16; ++r) {
      const int o_loc = og * 32 + (r & 3) + 8 * (r >> 2) + 4 * g;
      ob[(size_t)(o0 + o_loc) * 4096] = A[r] + beta_s[o_loc];
    }
  }
}

/* ---------------- host launcher ---------------- */
extern "C" void kernel_launch(void* const* d_in, const int* in_sizes, int n_in,
                              void* d_out, int out_size, void* d_ws, size_t ws_size,
                              hipStream_t stream) {
  (void)in_sizes; (void)n_in; (void)out_size; (void)ws_size;
  const float* x        = (const float*)d_in[0];
  const float* gn_g     = (const float*)d_in[1];
  const float* gn_b     = (const float*)d_in[2];
  const float* qkv_w    = (const float*)d_in[3];
  const float* qkv_bn_g = (const float*)d_in[4];
  const float* qkv_bn_b = (const float*)d_in[5];
  const float* qkv_rm   = (const float*)d_in[6];
  const float* qkv_rv   = (const float*)d_in[7];
  const float* proj_w   = (const float*)d_in[8];
  const float* proj_bn_g = (const float*)d_in[9];
  const float* proj_bn_b = (const float*)d_in[10];
  const float* proj_rm  = (const float*)d_in[11];
  const float* proj_rv  = (const float*)d_in[12];

  char* ws = (char*)d_ws;
  float* part  = (float*)ws;
  float* stats = (float*)(ws + 4096);
  bf16* qw = (bf16*)(ws + 8192);
  bf16* kw = (bf16*)(ws + 8192 + (1u << 20));
  bf16* vw = (bf16*)(ws + 8192 + (2u << 20));
  bf16* xc = (bf16*)(ws + 8192 + (6u << 20));

  k_stats_partial<<<256, 256, 0, stream>>>(x, part);
  k_stats_final<<<1, 256, 0, stream>>>(part, stats);
  k_qkv<<<512, 256, 0, stream>>>(x, gn_g, gn_b, qkv_w, qkv_bn_g, qkv_bn_b,
                                 qkv_rm, qkv_rv, stats, qw, kw, vw);
  k_attn<<<1024, 512, 0, stream>>>(qw, kw, vw, x, xc);
  k_proj<<<512, 256, 0, stream>>>(xc, proj_w, proj_bn_g, proj_bn_b,
                                  proj_rm, proj_rv, (float*)d_out);
}

// Round 10
// 85.911 us; speedup vs baseline: 2.2392x; 2.2392x over previous
//
#include <hip/hip_runtime.h>
#include <hip/hip_bf16.h>

typedef __bf16 bf16;
typedef __bf16 bf16x4 __attribute__((ext_vector_type(4)));
typedef __bf16 bf16x8 __attribute__((ext_vector_type(8)));
typedef float  f32x16 __attribute__((ext_vector_type(16)));

#define MFMA32 __builtin_amdgcn_mfma_f32_32x32x16_bf16
#define EPSV 1e-5f
#define QSCALE 0.36067376022224085f  /* 0.25 * log2(e) */

__device__ __forceinline__ f32x16 fzero16() {
  f32x16 z;
#pragma unroll
  for (int i = 0; i < 16; ++i) z[i] = 0.f;
  return z;
}

/* ---------------- kernel 1a: per-batch partial sums over x1 ---------------- */
__global__ __launch_bounds__(256) void k_stats_partial(const float* __restrict__ x,
                                                       float* __restrict__ part) {
  const int b = blockIdx.x >> 5, k = blockIdx.x & 31;
  const float* p = x + (size_t)b * 256 * 4096 + k * 8192;
  const int t = threadIdx.x;
  float s = 0.f, q = 0.f;
#pragma unroll
  for (int j = 0; j < 8; ++j) {
    float4 v = ((const float4*)p)[t + j * 256];
    s += v.x + v.y + v.z + v.w;
    q += v.x * v.x + v.y * v.y + v.z * v.z + v.w * v.w;
  }
  __shared__ float ls[256], lq[256];
  ls[t] = s; lq[t] = q;
  __syncthreads();
  for (int off = 128; off > 0; off >>= 1) {
    if (t < off) { ls[t] += ls[t + off]; lq[t] += lq[t + off]; }
    __syncthreads();
  }
  if (t == 0) { part[blockIdx.x * 2] = ls[0]; part[blockIdx.x * 2 + 1] = lq[0]; }
}

/* ---------------- kernel 1b: finalize mu / rstd per batch ---------------- */
__global__ __launch_bounds__(256) void k_stats_final(const float* __restrict__ part,
                                                     float* __restrict__ stats) {
  const int t = threadIdx.x, b = t >> 5, k = t & 31;
  float s = part[(b * 32 + k) * 2], q = part[(b * 32 + k) * 2 + 1];
  for (int off = 16; off > 0; off >>= 1) {
    s += __shfl_down(s, off, 32);
    q += __shfl_down(q, off, 32);
  }
  if (k == 0) {
    const float inv_n = 1.f / 262144.f;
    const float mu = s * inv_n;
    const float var = q * inv_n - mu * mu;
    stats[b * 2] = mu;
    stats[b * 2 + 1] = rsqrtf(var + EPSV);
  }
}

/* ------- kernel 2: GN-normalize x1, qkv matmul + BN, emit q/k/v bf16 -------
   V written in MFMA-FRAGMENT-MAJOR layout: vf[IT][f][lane][16B], where
   slot j of lane l = V[c=(l&31)+32*(f&1)][m=(j&3)+4*(l>>5)+8*(j>>2)+16*(f>>1)]
   (IT = global 32-key tile). Attention then loads V fully coalesced.        */
__global__ __launch_bounds__(256) void k_qkv(
    const float* __restrict__ x, const float* __restrict__ gn_g, const float* __restrict__ gn_b,
    const float* __restrict__ qkv_w, const float* __restrict__ bn_g, const float* __restrict__ bn_b,
    const float* __restrict__ bn_rm, const float* __restrict__ bn_rv,
    const float* __restrict__ stats,
    bf16* __restrict__ qw, bf16* __restrict__ kw, bf16* __restrict__ vw) {
  const int b = blockIdx.x >> 6, tile = blockIdx.x & 63;
  const int n0 = tile * 64, t = threadIdx.x;
  __shared__ float xn[64][68];
  __shared__ float W[64][96];
  __shared__ float beta_s[96];
  const float mu = stats[b * 2], rstd = stats[b * 2 + 1];
  {
    const int c = t >> 2, f = t & 3;
    const float A = rstd * gn_g[c], B = gn_b[c] - mu * A;
    const float* xr = x + ((size_t)b * 256 + c) * 4096 + n0;
#pragma unroll
    for (int j = 0; j < 4; ++j) {
      float4 v = ((const float4*)xr)[f * 4 + j];
      const int nb = f * 16 + j * 4;
      xn[c][nb + 0] = v.x * A + B; xn[c][nb + 1] = v.y * A + B;
      xn[c][nb + 2] = v.z * A + B; xn[c][nb + 3] = v.w * A + B;
    }
  }
  for (int oc = t; oc < 96 * 8; oc += 256) {
    const int o = oc >> 3, ch = (oc & 7) * 8;
    const float inv = bn_g[o] * rsqrtf(bn_rv[o] + EPSV);
    if (ch == 0) beta_s[o] = bn_b[o] - bn_rm[o] * inv;
    const float* wr = qkv_w + o * 64 + ch;
#pragma unroll
    for (int i = 0; i < 8; ++i) W[ch + i][o] = wr[i] * inv;
  }
  __syncthreads();
  const int o_l = t & 31, ng = t >> 5;
#pragma unroll 1
  for (int p = 0; p < 3; ++p) {
    const int o = p * 32 + o_l;
    float acc[8];
#pragma unroll
    for (int j = 0; j < 8; ++j) acc[j] = 0.f;
    for (int c = 0; c < 64; ++c) {
      const float wv = W[c][o];
      const float* xr = &xn[c][ng * 8];
#pragma unroll
      for (int j = 0; j < 8; ++j) acc[j] += wv * xr[j];
    }
    const float beta = beta_s[o];
    const int nb = n0 + ng * 8;
    if (p == 0) {
      if (o < 16) {
#pragma unroll
        for (int j = 0; j < 8; ++j)
          qw[((size_t)b * 4096 + nb + j) * 16 + o] = (bf16)((acc[j] + beta) * QSCALE);
      } else {
#pragma unroll
        for (int j = 0; j < 8; ++j)
          kw[((size_t)b * 4096 + nb + j) * 16 + (o - 16)] = (bf16)(acc[j] + beta);
      }
    } else {
      const int c = (p - 1) * 32 + o_l;
      /* fragment-major V store: thread owns (c, keys nb..nb+7) */
      const int IT = nb >> 5;             /* global 32-key tile   */
      const int m4 = nb & 31;             /* 0,8,16,24            */
      const int f  = ((m4 >> 4) << 1) + (c >> 5);
      const int b3 = (m4 >> 3) & 1;
      char* base = (char*)vw + (size_t)b * 524288 + (size_t)IT * 4096 +
                   f * 1024 + (c & 31) * 16 + b3 * 8;
      bf16x4 pk0, pk1;
#pragma unroll
      for (int i = 0; i < 4; ++i) {
        pk0[i] = (bf16)(acc[i] + beta);       /* keys m4..m4+3  -> lane c&31      */
        pk1[i] = (bf16)(acc[4 + i] + beta);   /* keys m4+4..+7  -> lane (c&31)+32 */
      }
      *(bf16x4*)base = pk0;
      *(bf16x4*)(base + 512) = pk1;
    }
  }
}

/* --------------- kernel 3: LDS-free flash attention, coalesced + prefetch ----
   grid 512 (XCD-swizzled, batch-per-XCD); 512 thr = 8 waves
   = 2 q-subtiles x 4 key-ranges (R8-proven stream structure: 2 waves share
   each K/V stream; 2 blocks/CU in near-lockstep share it again via L1/L2).
   Main loop: coalesced K (1KB) + fragment-major V (4x coalesced 1KB), BOTH
   prefetched one 32-key tile ahead in registers -> no exposed L2 latency.
   Zero LDS ops / barriers in loop. End: in-LDS split-K combine + fused
   relu(x2) transpose.                                                        */
__global__ __launch_bounds__(512, 4) void k_attn(
    const bf16* __restrict__ qw, const bf16* __restrict__ kw,
    const bf16* __restrict__ vw, const float* __restrict__ x,
    bf16* __restrict__ xc) {
  __shared__ __align__(16) char smem[33792];   /* 8x4KB Opart + 8x128B l */
  const int orig = blockIdx.x;
  const int wg = (orig & 7) * 64 + (orig >> 3);  /* XCD j <- batch j */
  const int b = wg >> 6, qblk = wg & 63;
  const int t = threadIdx.x;
  const int wid = t >> 6, l = t & 63, ln = l & 31, g = l >> 5;
  const int qsub = wid & 1, kr = wid >> 1;
  const int m0 = kr * 1024;

  const bf16* qb = qw + (size_t)b * 4096 * 16;
  const char* kb = (const char*)(kw + (size_t)b * 4096 * 16);
  const char* vfb = (const char*)vw + (size_t)b * 524288;

  const char* kptr = kb + (size_t)(m0 + ln) * 32 + 16 * g;
  const char* vptr = vfb + (size_t)(m0 >> 5) * 4096 + l * 16;

  const int nq = qblk * 64 + qsub * 32 + ln;
  const bf16x8 qf = *(const bf16x8*)(qb + (size_t)nq * 16 + g * 8);

  f32x16 O0 = fzero16(), O1 = fzero16();
  float l_run = 0.f;

  /* prologue: load tile 0's fragments */
  uint4 kc  = *(const uint4*)kptr;
  uint4 va0 = *(const uint4*)(vptr);
  uint4 vb0 = *(const uint4*)(vptr + 1024);
  uint4 va1 = *(const uint4*)(vptr + 2048);
  uint4 vb1 = *(const uint4*)(vptr + 3072);

#pragma unroll 2
  for (int it = 0; it < 32; ++it) {
    /* prefetch tile it+1 (registers) — issued before any use of tile it */
    uint4 kn, wa0, wb0, wa1, wb1;
    if (it + 1 < 32) {
      kn  = *(const uint4*)(kptr + (it + 1) * 1024);
      wa0 = *(const uint4*)(vptr + (it + 1) * 4096);
      wb0 = *(const uint4*)(vptr + (it + 1) * 4096 + 1024);
      wa1 = *(const uint4*)(vptr + (it + 1) * 4096 + 2048);
      wb1 = *(const uint4*)(vptr + (it + 1) * 4096 + 3072);
    }
    /* QK^T: S[key m][query n], n = ln lane-local */
    f32x16 S = MFMA32(__builtin_bit_cast(bf16x8, kc), qf, fzero16(), 0, 0, 0);
    float ts = 0.f;
#pragma unroll
    for (int r = 0; r < 16; ++r) { S[r] = __builtin_amdgcn_exp2f(S[r]); ts += S[r]; }
    ts += __shfl_xor(ts, 32, 64);
    l_run += ts;
    bf16x8 pb0, pb1;
#pragma unroll
    for (int r = 0; r < 8; ++r) { pb0[r] = (bf16)S[r]; pb1[r] = (bf16)S[r + 8]; }
    /* PV: 4 MFMAs, fragments straight from (prefetched) registers */
    O0 = MFMA32(__builtin_bit_cast(bf16x8, va0), pb0, O0, 0, 0, 0);
    O1 = MFMA32(__builtin_bit_cast(bf16x8, vb0), pb0, O1, 0, 0, 0);
    O0 = MFMA32(__builtin_bit_cast(bf16x8, va1), pb1, O0, 0, 0, 0);
    O1 = MFMA32(__builtin_bit_cast(bf16x8, vb1), pb1, O1, 0, 0, 0);
    kc = kn; va0 = wa0; vb0 = wb0; va1 = wa1; vb1 = wb1;
  }

  /* partials into own LDS slice: Opart[wid][n 32][16 x 8B chunks] swizzled */
  {
    char* orow = smem + wid * 4096 + ln * 128;
    const int msk = 2 * (ln & 7);
#pragma unroll
    for (int h = 0; h < 2; ++h) {
      const f32x16& O = h ? O1 : O0;
#pragma unroll
      for (int j = 0; j < 4; ++j) {
        bf16x4 e;
#pragma unroll
        for (int i = 0; i < 4; ++i) e[i] = (bf16)O[4 * j + i];
        const int chunk = h * 8 + 2 * j + g;
        *(bf16x4*)(orow + ((chunk ^ msk) << 3)) = e;
      }
    }
    if (g == 0) *(float*)(smem + 32768 + wid * 128 + ln * 4) = l_run;
  }
  __syncthreads();

  /* combine 4 key-range partials per q-subtile -> xc[:,0:64] */
  {
    const int qs = t >> 8, tt = t & 255;
    const int n = tt >> 3, k8 = tt & 7;
    float L = 0.f;
    float acc[8];
#pragma unroll
    for (int e = 0; e < 8; ++e) acc[e] = 0.f;
#pragma unroll
    for (int kr_ = 0; kr_ < 4; ++kr_) {
      const int wsrc = kr_ * 2 + qs;
      L += *(const float*)(smem + 32768 + wsrc * 128 + n * 4);
      const bf16x8 v = *(const bf16x8*)(smem + wsrc * 4096 + n * 128 +
                                        (((2 * k8) ^ (2 * (n & 7))) << 3));
#pragma unroll
      for (int e = 0; e < 8; ++e) acc[e] += (float)v[e];
    }
    const float rL = 1.0f / L;
    bf16x8 o8;
#pragma unroll
    for (int e = 0; e < 8; ++e) o8[e] = (bf16)fmaxf(acc[e] * rL, 0.f);
    *(bf16x8*)(xc + ((size_t)b * 4096 + qblk * 64 + qs * 32 + n) * 256 + k8 * 8) = o8;
  }
  __syncthreads();

  /* fused prep_x2: relu(x2) -> bf16 transpose into xc[n][64:256] */
  {
    unsigned* tile_u = (unsigned*)smem;  /* [64 n][97 stride] words */
    const float* xb = x + ((size_t)b * 256 + 64) * 4096 + qblk * 64;
#pragma unroll
    for (int i = 0; i < 3; ++i) {
      const int idx = i * 512 + t;
      const int cp = idx >> 4, f = idx & 15;
      const float4 a = *(const float4*)(xb + (size_t)(2 * cp) * 4096 + f * 4);
      const float4 c4 = *(const float4*)(xb + (size_t)(2 * cp + 1) * 4096 + f * 4);
      const float av[4] = {a.x, a.y, a.z, a.w};
      const float cv[4] = {c4.x, c4.y, c4.z, c4.w};
#pragma unroll
      for (int e = 0; e < 4; ++e) {
        const unsigned u =
            (unsigned)__builtin_bit_cast(unsigned short, (bf16)fmaxf(av[e], 0.f)) |
            ((unsigned)__builtin_bit_cast(unsigned short, (bf16)fmaxf(cv[e], 0.f)) << 16);
        tile_u[(f * 4 + e) * 97 + cp] = u;
      }
    }
    __syncthreads();
#pragma unroll
    for (int i = 0; i < 3; ++i) {
      const int idx = i * 512 + t;
      const int n = idx / 24, q = idx % 24;
      const uint4 d = *(const uint4*)&tile_u[n * 97 + q * 4];
      *(uint4*)(xc + ((size_t)b * 4096 + qblk * 64 + n) * 256 + 64 + q * 8) = d;
    }
  }
}

/* ---------- kernel 4: proj matmul (MFMA bf16) + BN, 128n x 128o tile ---------- */
__global__ __launch_bounds__(256, 2) void k_proj(
    const bf16* __restrict__ xc, const float* __restrict__ pw,
    const float* __restrict__ bn_g, const float* __restrict__ bn_b,
    const float* __restrict__ bn_rm, const float* __restrict__ bn_rv,
    float* __restrict__ out) {
  const int orig = blockIdx.x;
  const int wg = (orig & 7) * 64 + (orig >> 3);  /* XCD swizzle, 512 blocks */
  const int b = wg >> 6, rem = wg & 63, nt = rem >> 1, oh = rem & 1;
  const int n0 = nt * 128, o0 = oh * 128;
  const int t = threadIdx.x, w = t >> 6, l = t & 63, ln = l & 31, g = l >> 5;

  __shared__ __align__(16) bf16 pws[128 * 256];
  __shared__ float beta_s[128];

  {
    const int o = t >> 1, half = t & 1;
    const float inv = bn_g[o0 + o] * rsqrtf(bn_rv[o0 + o] + EPSV);
    if (half == 0) beta_s[o] = bn_b[o0 + o] - bn_rm[o0 + o] * inv;
    const float* wr = pw + (size_t)(o0 + o) * 256 + half * 128;
    const int s_hh = (o & 15) * 8;
#pragma unroll
    for (int j = 0; j < 16; ++j) {
      const float4 a = ((const float4*)wr)[j * 2];
      const float4 c4 = ((const float4*)wr)[j * 2 + 1];
      bf16x8 v8;
      v8[0] = (bf16)(a.x * inv);  v8[1] = (bf16)(a.y * inv);
      v8[2] = (bf16)(a.z * inv);  v8[3] = (bf16)(a.w * inv);
      v8[4] = (bf16)(c4.x * inv); v8[5] = (bf16)(c4.y * inv);
      v8[6] = (bf16)(c4.z * inv); v8[7] = (bf16)(c4.w * inv);
      *(bf16x8*)&pws[o * 256 + ((half * 128 + j * 8) ^ s_hh)] = v8;
    }
  }
  __syncthreads();

  const bf16* xrow = xc + ((size_t)b * 4096 + n0 + w * 32 + ln) * 256;
  const int sw = (ln & 15) * 8;
  f32x16 acc0 = fzero16(), acc1 = fzero16(), acc2 = fzero16(), acc3 = fzero16();
#pragma unroll 4
  for (int ck = 0; ck < 256; ck += 16) {
    const bf16x8 bfrag = *(const bf16x8*)(xrow + ck + g * 8);
    const int cidx = (ck + g * 8) ^ sw;
    const bf16x8 a0 = *(const bf16x8*)&pws[(ln) * 256 + cidx];
    const bf16x8 a1 = *(const bf16x8*)&pws[(32 + ln) * 256 + cidx];
    const bf16x8 a2 = *(const bf16x8*)&pws[(64 + ln) * 256 + cidx];
    const bf16x8 a3 = *(const bf16x8*)&pws[(96 + ln) * 256 + cidx];
    acc0 = MFMA32(a0, bfrag, acc0, 0, 0, 0);
    acc1 = MFMA32(a1, bfrag, acc1, 0, 0, 0);
    acc2 = MFMA32(a2, bfrag, acc2, 0, 0, 0);
    acc3 = MFMA32(a3, bfrag, acc3, 0, 0, 0);
  }
  const int ncol = n0 + w * 32 + ln;
  float* ob = out + (size_t)b * 256 * 4096 + ncol;
#pragma unroll
  for (int og = 0; og < 4; ++og) {
    const f32x16& A = og == 0 ? acc0 : og == 1 ? acc1 : og == 2 ? acc2 : acc3;
#pragma unroll
    for (int r = 0; r < 16; ++r) {
      const int o_loc = og * 32 + (r & 3) + 8 * (r >> 2) + 4 * g;
      ob[(size_t)(o0 + o_loc) * 4096] = A[r] + beta_s[o_loc];
    }
  }
}

/* ---------------- host launcher ---------------- */
extern "C" void kernel_launch(void* const* d_in, const int* in_sizes, int n_in,
                              void* d_out, int out_size, void* d_ws, size_t ws_size,
                              hipStream_t stream) {
  (void)in_sizes; (void)n_in; (void)out_size; (void)ws_size;
  const float* x        = (const float*)d_in[0];
  const float* gn_g     = (const float*)d_in[1];
  const float* gn_b     = (const float*)d_in[2];
  const float* qkv_w    = (const float*)d_in[3];
  const float* qkv_bn_g = (const float*)d_in[4];
  const float* qkv_bn_b = (const float*)d_in[5];
  const float* qkv_rm   = (const float*)d_in[6];
  const float* qkv_rv   = (const float*)d_in[7];
  const float* proj_w   = (const float*)d_in[8];
  const float* proj_bn_g = (const float*)d_in[9];
  const float* proj_bn_b = (const float*)d_in[10];
  const float* proj_rm  = (const float*)d_in[11];
  const float* proj_rv  = (const float*)d_in[12];

  char* ws = (char*)d_ws;
  float* part  = (float*)ws;
  float* stats = (float*)(ws + 4096);
  bf16* qw = (bf16*)(ws + 8192);
  bf16* kw = (bf16*)(ws + 8192 + (1u << 20));
  bf16* vw = (bf16*)(ws + 8192 + (2u << 20));
  bf16* xc = (bf16*)(ws + 8192 + (6u << 20));

  k_stats_partial<<<256, 256, 0, stream>>>(x, part);
  k_stats_final<<<1, 256, 0, stream>>>(part, stats);
  k_qkv<<<512, 256, 0, stream>>>(x, gn_g, gn_b, qkv_w, qkv_bn_g, qkv_bn_b,
                                 qkv_rm, qkv_rv, stats, qw, kw, vw);
  k_attn<<<512, 512, 0, stream>>>(qw, kw, vw, x, xc);
  k_proj<<<512, 256, 0, stream>>>(xc, proj_w, proj_bn_g, proj_bn_b,
                                  proj_rm, proj_rv, (float*)d_out);
}